// Round 1
// 2860.093 us; speedup vs baseline: 1.4667x; 1.4667x over previous
//
#include <hip/hip_runtime.h>
#include <math.h>

#define NN 100000        // nodes
#define NE 1600000       // edges
#define MNZ 800000       // nnz per motif
#define NM 13            // motifs
// C_IN = C_OUT = D = 64; K_total = 14*64 = 896; out cols = 13*64 = 832

typedef __attribute__((ext_vector_type(8))) short short8;
typedef __attribute__((ext_vector_type(4))) float floatx4;

__device__ __forceinline__ unsigned short f2bf(float f) {
    unsigned int u = __float_as_uint(f);
    u += 0x7FFFu + ((u >> 16) & 1u);   // round-to-nearest-even
    return (unsigned short)(u >> 16);
}

// ---------------- K1: XW = x @ W_rel  (N x 64 @ 64 x 64, fp32) ----------------
__global__ __launch_bounds__(256) void k_xw(const float* __restrict__ x,
                                            const float* __restrict__ W,
                                            float* __restrict__ out) {
    __shared__ float Wl[64 * 64];
    __shared__ float xl[4][64];
    int t = threadIdx.x;
    for (int s = t; s < 4096; s += 256) Wl[s] = W[s];
    int nl = t >> 6, d = t & 63;
    int n = blockIdx.x * 4 + nl;
    xl[nl][d] = x[n * 64 + d];
    __syncthreads();
    float acc = 0.f;
#pragma unroll
    for (int k = 0; k < 64; ++k) acc = fmaf(xl[nl][k], Wl[k * 64 + d], acc);
    out[n * 64 + d] = acc;
}

// ---------------- CSR build: histogram ----------------------------------------
__global__ __launch_bounds__(256) void k_hist_m(const int* __restrict__ mdst,
                                                int* __restrict__ cnt) {
    int m = blockIdx.y;
    int j = blockIdx.x * 256 + threadIdx.x;
    int d = mdst[(long long)m * MNZ + j];
    atomicAdd(&cnt[m * NN + d], 1);
}

__global__ __launch_bounds__(256) void k_hist_e(const int* __restrict__ ei,
                                                int* __restrict__ cnt) {
    int e = blockIdx.x * 256 + threadIdx.x;
    atomicAdd(&cnt[ei[NE + e]], 1);
}

// ---------------- CSR build: segment allocation (block scan + bump cursor) ----
__global__ __launch_bounds__(256) void k_alloc(const int* __restrict__ cnt,
                                               int* __restrict__ off,
                                               int* __restrict__ fill,
                                               int* __restrict__ cursor, int n) {
    __shared__ int sc[256];
    __shared__ int sbase;
    int m = blockIdx.y;
    int t = threadIdx.x;
    int d = blockIdx.x * 256 + t;
    int c = (d < n) ? cnt[(long long)m * n + d] : 0;
    sc[t] = c;
    __syncthreads();
    for (int s = 1; s < 256; s <<= 1) {
        int add = (t >= s) ? sc[t - s] : 0;
        __syncthreads();
        sc[t] += add;
        __syncthreads();
    }
    int incl = sc[t];
    int excl = incl - c;
    if (t == 255) sbase = atomicAdd(cursor + m, incl);  // incl == block total at t=255
    __syncthreads();
    if (d < n) {
        int o = sbase + excl;
        off[(long long)m * n + d] = o;
        fill[(long long)m * n + d] = o;
    }
}

// ---------------- CSR build: scatter {src,val} entries ------------------------
__global__ __launch_bounds__(256) void k_scat_m(const int* __restrict__ msrc,
                                                const int* __restrict__ mdst,
                                                const float* __restrict__ mval,
                                                int* __restrict__ fill,
                                                int2* __restrict__ sm) {
    int m = blockIdx.y;
    long long idx = (long long)m * MNZ + blockIdx.x * 256 + threadIdx.x;
    int d = mdst[idx];
    int p = atomicAdd(&fill[m * NN + d], 1);
    sm[(long long)m * MNZ + p] = make_int2(msrc[idx], __float_as_int(mval[idx]));
}

__global__ __launch_bounds__(256) void k_scat_e(const int* __restrict__ ei,
                                                const float* __restrict__ ew,
                                                int* __restrict__ fill,
                                                int2* __restrict__ se) {
    int e = blockIdx.x * 256 + threadIdx.x;
    int d = ei[NE + e];
    int p = atomicAdd(&fill[d], 1);
    se[p] = make_int2(ei[e], __float_as_int(ew[e]));
}

// ---------------- K2': edge gather  H[d] = sum w * XW[src]  -------------------
// One 16-lane quad per dst node; lane handles 4 channels (float4).
__global__ __launch_bounds__(256) void k_gath_e(const int2* __restrict__ se,
                                                const int* __restrict__ off,
                                                const int* __restrict__ cnt,
                                                const float* __restrict__ XW,
                                                float* __restrict__ H) {
    int sub = threadIdx.x >> 4, l = threadIdx.x & 15;
    int d = blockIdx.x * 16 + sub;
    int o = off[d], c = cnt[d];
    const int2* ep = se + o;
    floatx4 acc = (floatx4)0.f;
    int e = 0;
    for (; e + 1 < c; e += 2) {
        int2 a = ep[e], b = ep[e + 1];
        floatx4 ha = *(const floatx4*)&XW[(long long)a.x * 64 + l * 4];
        floatx4 hb = *(const floatx4*)&XW[(long long)b.x * 64 + l * 4];
        float va = __int_as_float(a.y), vb = __int_as_float(b.y);
#pragma unroll
        for (int q = 0; q < 4; ++q) acc[q] = fmaf(va, ha[q], acc[q]);
#pragma unroll
        for (int q = 0; q < 4; ++q) acc[q] = fmaf(vb, hb[q], acc[q]);
    }
    if (e < c) {
        int2 a = ep[e];
        floatx4 ha = *(const floatx4*)&XW[(long long)a.x * 64 + l * 4];
        float va = __int_as_float(a.y);
#pragma unroll
        for (int q = 0; q < 4; ++q) acc[q] = fmaf(va, ha[q], acc[q]);
    }
    *(floatx4*)&H[(long long)d * 64 + l * 4] = acc;
}

// ---------------- K3: h = h*norm + x@root + bias; Rb chunk0 = bf16(h) ---------
__global__ __launch_bounds__(256) void k_fin(const float* __restrict__ x,
                                             const float* __restrict__ root,
                                             const float* __restrict__ bias,
                                             const int* __restrict__ cnt_e,
                                             float* __restrict__ H,
                                             unsigned short* __restrict__ Rb) {
    __shared__ float Wl[64 * 64];
    __shared__ float xl[4][64];
    int t = threadIdx.x;
    for (int s = t; s < 4096; s += 256) Wl[s] = root[s];
    int nl = t >> 6, d = t & 63;
    int n = blockIdx.x * 4 + nl;
    xl[nl][d] = x[n * 64 + d];
    __syncthreads();
    float acc = 0.f;
#pragma unroll
    for (int k = 0; k < 64; ++k) acc = fmaf(xl[nl][k], Wl[k * 64 + d], acc);
    int dg = cnt_e[n];
    float nm = dg > 0 ? 1.0f / (float)dg : 0.f;
    long long idx = (long long)n * 64 + d;
    float hv = H[idx] * nm + acc + bias[d];
    H[idx] = hv;
    Rb[idx] = f2bf(hv);   // chunk 0 of chunk-major Rb [14][NN][64]
}

// ---------------- K4': motif gather  Rb[m+1][d] = bf16(sum v * H[src]) --------
__global__ __launch_bounds__(256) void k_gath_m(const int2* __restrict__ sm,
                                                const int* __restrict__ off,
                                                const int* __restrict__ cnt,
                                                const float* __restrict__ H,
                                                unsigned short* __restrict__ Rb) {
    int m = blockIdx.y;
    int sub = threadIdx.x >> 4, l = threadIdx.x & 15;
    int d = blockIdx.x * 16 + sub;
    long long mi = (long long)m * NN + d;
    int o = off[mi], c = cnt[mi];
    const int2* ep = sm + (long long)m * MNZ + o;
    floatx4 acc = (floatx4)0.f;
    int e = 0;
    for (; e + 1 < c; e += 2) {
        int2 a = ep[e], b = ep[e + 1];
        floatx4 ha = *(const floatx4*)&H[(long long)a.x * 64 + l * 4];
        floatx4 hb = *(const floatx4*)&H[(long long)b.x * 64 + l * 4];
        float va = __int_as_float(a.y), vb = __int_as_float(b.y);
#pragma unroll
        for (int q = 0; q < 4; ++q) acc[q] = fmaf(va, ha[q], acc[q]);
#pragma unroll
        for (int q = 0; q < 4; ++q) acc[q] = fmaf(vb, hb[q], acc[q]);
    }
    if (e < c) {
        int2 a = ep[e];
        floatx4 ha = *(const floatx4*)&H[(long long)a.x * 64 + l * 4];
        float va = __int_as_float(a.y);
#pragma unroll
        for (int q = 0; q < 4; ++q) acc[q] = fmaf(va, ha[q], acc[q]);
    }
    unsigned int lo = (unsigned int)f2bf(acc[0]) | ((unsigned int)f2bf(acc[1]) << 16);
    unsigned int hi = (unsigned int)f2bf(acc[2]) | ((unsigned int)f2bf(acc[3]) << 16);
    *(uint2*)&Rb[((long long)(m + 1) * NN + d) * 64 + l * 4] = make_uint2(lo, hi);
}

// ---------------- K5: build WT (Wbig^T) in bf16: [832 cols][896 k] ------------
__global__ void k_wt(const float* __restrict__ mW, unsigned short* __restrict__ WT) {
    int n = blockIdx.y;                        // 0..831
    int k = blockIdx.x * 128 + threadIdx.x;    // 0..895
    int i = (n >> 6) + 1;
    int d = n & 63;
    int r = k >> 6;
    int kk = k & 63;
    float v = 0.f;
    if (r != i) {
        int j = (r < i) ? r : r - 1;
        v = mW[((long long)(i - 1) * 832 + (j * 64 + kk)) * 64 + d];
    }
    WT[(long long)n * 896 + k] = f2bf(v);
}

// ---------------- K6: fused GEMM + mw + attention -----------------------------
// grid (13, 782): x = motif col-block, y = 128-row tile. 256 thr = 4 waves.
// A now read directly as bf16 from chunk-major Rb [14][NN][64].
#define BM 128
#define LDA 72   // bf16 elems per LDS row (72*2=144B, 16B aligned, 2-way banks)

__global__ __launch_bounds__(256) void k_gemm(const unsigned short* __restrict__ Rb,
                                              const unsigned short* __restrict__ WT,
                                              const float* __restrict__ wa,
                                              const float* __restrict__ ba,
                                              const float* __restrict__ mb,
                                              float* __restrict__ out) {
    int im1 = blockIdx.x;          // 0..12, motif i = im1+1
    int i = im1 + 1;
    int row0 = blockIdx.y * BM;
    int t = threadIdx.x;
    int w = t >> 6;
    int lane = t & 63;
    int quad = lane >> 4;
    int l16 = lane & 15;

    __shared__ __align__(16) unsigned short Al[BM * LDA];
    __shared__ __align__(16) unsigned short Bl[64 * LDA];
    __shared__ __align__(16) unsigned short waTl[64 * LDA];

    // stage wa^T once: waTl[d][k] = bf16(wa[k][d])
    for (int s = t; s < 4096; s += 256) {
        int k = s >> 6, d = s & 63;
        waTl[d * LDA + k] = f2bf(wa[s]);
    }

    floatx4 acc[2][4];   // c accumulator: [m-tile][n-tile]
    floatx4 mwa[2][4];   // mw accumulator
#pragma unroll
    for (int a = 0; a < 2; ++a)
#pragma unroll
        for (int b = 0; b < 4; ++b) { acc[a][b] = (floatx4)0.f; mwa[a][b] = (floatx4)0.f; }

    // kb 0..13: main K loop (c).  kb==14: mw pass (A chunk r=i, B = wa^T).
    for (int kb = 0; kb < 15; ++kb) {
        int kchunk = (kb < 14) ? kb : i;
        __syncthreads();
        // stage A: 128 rows x 64 k, already bf16 (short8 global loads)
#pragma unroll
        for (int s = 0; s < 4; ++s) {
            int lin = t + s * 256;           // short8 index 0..1023
            int rr = lin >> 3;               // row 0..127
            int k8 = (lin & 7) * 8;          // k 0..56
            int grow = row0 + rr;
            short8 v = (short8)0;
            if (grow < NN) v = *(const short8*)&Rb[((long long)kchunk * NN + grow) * 64 + k8];
            *(short8*)&Al[rr * LDA + k8] = v;
        }
        if (kb < 14) {
            // stage B chunk from WT (already bf16): 64 rows x 64 k
#pragma unroll
            for (int s = 0; s < 4; ++s) {
                int lin4 = t + s * 256;      // ushort4 index 0..1023
                int n = lin4 >> 4;
                int k4 = (lin4 & 15) * 4;
                const unsigned short* src = &WT[(long long)(im1 * 64 + n) * 896 + kb * 64 + k4];
                *(unsigned long long*)&Bl[n * LDA + k4] = *(const unsigned long long*)src;
            }
        }
        __syncthreads();
#pragma unroll
        for (int kk = 0; kk < 64; kk += 32) {
            short8 af[2];
#pragma unroll
            for (int mt = 0; mt < 2; ++mt)
                af[mt] = *(const short8*)&Al[((w * 2 + mt) * 16 + l16) * LDA + kk + quad * 8];
            if (kb < 14) {
#pragma unroll
                for (int nt = 0; nt < 4; ++nt) {
                    short8 bf = *(const short8*)&Bl[(nt * 16 + l16) * LDA + kk + quad * 8];
#pragma unroll
                    for (int mt = 0; mt < 2; ++mt)
                        acc[mt][nt] = __builtin_amdgcn_mfma_f32_16x16x32_bf16(af[mt], bf, acc[mt][nt], 0, 0, 0);
                }
            } else {
#pragma unroll
                for (int nt = 0; nt < 4; ++nt) {
                    short8 bf = *(const short8*)&waTl[(nt * 16 + l16) * LDA + kk + quad * 8];
#pragma unroll
                    for (int mt = 0; mt < 2; ++mt)
                        mwa[mt][nt] = __builtin_amdgcn_mfma_f32_16x16x32_bf16(af[mt], bf, mwa[mt][nt], 0, 0, 0);
                }
            }
        }
    }

    // epilogue: c += mb, mw += ba; att = sigmoid(sum_d mw*c); out = att*(mw-c)
#pragma unroll
    for (int mt = 0; mt < 2; ++mt) {
        float cv[4][4], mv[4][4];   // [nt][reg]
#pragma unroll
        for (int nt = 0; nt < 4; ++nt) {
            int col = nt * 16 + l16;
            float mbv = mb[im1 * 64 + col];
            float bav = ba[col];
#pragma unroll
            for (int r = 0; r < 4; ++r) {
                cv[nt][r] = acc[mt][nt][r] + mbv;
                mv[nt][r] = mwa[mt][nt][r] + bav;
            }
        }
        int grow_base = row0 + (w * 2 + mt) * 16 + quad * 4;
#pragma unroll
        for (int r = 0; r < 4; ++r) {
            float s = 0.f;
#pragma unroll
            for (int nt = 0; nt < 4; ++nt) s += mv[nt][r] * cv[nt][r];
            s += __shfl_xor(s, 1);
            s += __shfl_xor(s, 2);
            s += __shfl_xor(s, 4);
            s += __shfl_xor(s, 8);   // full 64-col row sum within the 16-lane quad group
            float att = 1.f / (1.f + __expf(-s));
            int grow = grow_base + r;
            if (grow < NN) {
#pragma unroll
                for (int nt = 0; nt < 4; ++nt)
                    out[(long long)grow * 832 + im1 * 64 + nt * 16 + l16] = att * (mv[nt][r] - cv[nt][r]);
            }
        }
    }
}

// ------------------------------------------------------------------------------
extern "C" void kernel_launch(void* const* d_in, const int* in_sizes, int n_in,
                              void* d_out, int out_size, void* d_ws, size_t ws_size,
                              hipStream_t stream) {
    const float* x    = (const float*)d_in[0];
    const int*   ei   = (const int*)d_in[1];
    const float* ew   = (const float*)d_in[2];
    const int*   msrc = (const int*)d_in[3];
    const int*   mdst = (const int*)d_in[4];
    const float* mval = (const float*)d_in[5];
    const float* Wrel = (const float*)d_in[6];
    const float* root = (const float*)d_in[7];
    const float* bias = (const float*)d_in[8];
    const float* wa   = (const float*)d_in[9];
    const float* ba   = (const float*)d_in[10];
    const float* mW   = (const float*)d_in[11];
    const float* mb   = (const float*)d_in[12];
    float* out = (float*)d_out;

    // workspace layout (~345 MB)
    unsigned short* Rb = (unsigned short*)d_ws;                 // [14][NN][64] bf16 (chunk-major)
    float* H  = (float*)(Rb + (size_t)14 * NN * 64);            // [NN][64] fp32
    float* XW = H + (size_t)NN * 64;                            // [NN][64] fp32
    unsigned short* WT = (unsigned short*)(XW + (size_t)NN * 64); // [832][896] bf16
    int2* sm = (int2*)(WT + (size_t)832 * 896);                 // [13][MNZ] {src,val}
    int2* se = sm + (size_t)NM * MNZ;                           // [NE] {src,w}
    int* cnt_m  = (int*)(se + NE);                              // [13][NN]
    int* cnt_e  = cnt_m + (size_t)NM * NN;                      // [NN]
    int* cursors = cnt_e + NN;                                  // [16]
    int* off_m  = cursors + 16;                                 // [13][NN]
    int* fill_m = off_m + (size_t)NM * NN;                      // [13][NN]
    int* off_e  = fill_m + (size_t)NM * NN;                     // [NN]
    int* fill_e = off_e + NN;                                   // [NN]

    // zero cnt_m + cnt_e + cursors in one shot (contiguous)
    hipMemsetAsync(cnt_m, 0, sizeof(int) * ((size_t)NM * NN + NN + 16), stream);

    k_xw<<<NN / 4, 256, 0, stream>>>(x, Wrel, XW);
    k_hist_m<<<dim3(MNZ / 256, NM), 256, 0, stream>>>(mdst, cnt_m);
    k_hist_e<<<NE / 256, 256, 0, stream>>>(ei, cnt_e);
    k_alloc<<<dim3((NN + 255) / 256, NM), 256, 0, stream>>>(cnt_m, off_m, fill_m, cursors, NN);
    k_alloc<<<dim3((NN + 255) / 256, 1), 256, 0, stream>>>(cnt_e, off_e, fill_e, cursors + NM, NN);
    k_scat_m<<<dim3(MNZ / 256, NM), 256, 0, stream>>>(msrc, mdst, mval, fill_m, sm);
    k_scat_e<<<NE / 256, 256, 0, stream>>>(ei, ew, fill_e, se);
    k_gath_e<<<NN / 16, 256, 0, stream>>>(se, off_e, cnt_e, XW, H);
    k_fin<<<NN / 4, 256, 0, stream>>>(x, root, bias, cnt_e, H, Rb);
    k_gath_m<<<dim3(NN / 16, NM), 256, 0, stream>>>(sm, off_m, cnt_m, H, Rb);
    k_wt<<<dim3(7, 832), 128, 0, stream>>>(mW, WT);
    k_gemm<<<dim3(NM, (NN + BM - 1) / BM), 256, 0, stream>>>(Rb, WT, wa, ba, mb, out);
}

// Round 2
// 2454.120 us; speedup vs baseline: 1.7093x; 1.1654x over previous
//
#include <hip/hip_runtime.h>
#include <math.h>

#define NN 100000        // nodes
#define NE 1600000       // edges
#define MNZ 800000       // nnz per motif
#define NM 13            // motifs
#define SLICE_W 12500    // NN / 8 — dst range owned by each XCD slice
// C_IN = C_OUT = D = 64; K_total = 14*64 = 896; out cols = 13*64 = 832

typedef __attribute__((ext_vector_type(8))) short short8;
typedef __attribute__((ext_vector_type(4))) float floatx4;

__device__ __forceinline__ unsigned short f2bf(float f) {
    unsigned int u = __float_as_uint(f);
    u += 0x7FFFu + ((u >> 16) & 1u);   // round-to-nearest-even
    return (unsigned short)(u >> 16);
}

// ---------------- K1: XW = x @ W_rel  (N x 64 @ 64 x 64, fp32) ----------------
__global__ __launch_bounds__(256) void k_xw(const float* __restrict__ x,
                                            const float* __restrict__ W,
                                            float* __restrict__ out) {
    __shared__ float Wl[64 * 64];
    __shared__ float xl[4][64];
    int t = threadIdx.x;
    for (int s = t; s < 4096; s += 256) Wl[s] = W[s];
    int nl = t >> 6, d = t & 63;
    int n = blockIdx.x * 4 + nl;
    xl[nl][d] = x[n * 64 + d];
    __syncthreads();
    float acc = 0.f;
#pragma unroll
    for (int k = 0; k < 64; ++k) acc = fmaf(xl[nl][k], Wl[k * 64 + d], acc);
    out[n * 64 + d] = acc;
}

// ---------------- CSR build: histogram ----------------------------------------
__global__ __launch_bounds__(256) void k_hist_m(const int* __restrict__ mdst,
                                                int* __restrict__ cnt) {
    int m = blockIdx.y;
    int j = blockIdx.x * 256 + threadIdx.x;
    int d = mdst[(long long)m * MNZ + j];
    atomicAdd(&cnt[m * NN + d], 1);
}

__global__ __launch_bounds__(256) void k_hist_e(const int* __restrict__ ei,
                                                int* __restrict__ cnt) {
    int e = blockIdx.x * 256 + threadIdx.x;
    atomicAdd(&cnt[ei[NE + e]], 1);
}

// ---------------- CSR build: segment allocation (block scan + bump cursor) ----
__global__ __launch_bounds__(256) void k_alloc(const int* __restrict__ cnt,
                                               int* __restrict__ off,
                                               int* __restrict__ fill,
                                               int* __restrict__ cursor, int n) {
    __shared__ int sc[256];
    __shared__ int sbase;
    int m = blockIdx.y;
    int t = threadIdx.x;
    int d = blockIdx.x * 256 + t;
    int c = (d < n) ? cnt[(long long)m * n + d] : 0;
    sc[t] = c;
    __syncthreads();
    for (int s = 1; s < 256; s <<= 1) {
        int add = (t >= s) ? sc[t - s] : 0;
        __syncthreads();
        sc[t] += add;
        __syncthreads();
    }
    int incl = sc[t];
    int excl = incl - c;
    if (t == 255) sbase = atomicAdd(cursor + m, incl);  // incl == block total at t=255
    __syncthreads();
    if (d < n) {
        int o = sbase + excl;
        off[(long long)m * n + d] = o;
        fill[(long long)m * n + d] = o;
    }
}

// ---------------- CSR build: scatter {src,val} entries ------------------------
// XCD-slice partitioned: slice = blockIdx.x & 7 owns dst in [slice*12500, ...).
// Blocks round-robin across the 8 XCDs by linear id (grid.x % 8 == 0 keeps the
// phase stable across blockIdx.y), so every CSR output line is written from ONE
// XCD's L2 -> full-line writebacks instead of masked partial-line RMW.
__global__ __launch_bounds__(256) void k_scat_m(const int* __restrict__ msrc,
                                                const int* __restrict__ mdst,
                                                const float* __restrict__ mval,
                                                int* __restrict__ fill,
                                                int2* __restrict__ sm) {
    int m = blockIdx.y;
    int slice = blockIdx.x & 7;
    long long idx = (long long)m * MNZ + (long long)(blockIdx.x >> 3) * 256 + threadIdx.x;
    int d = mdst[idx];
    if (d / SLICE_W == slice) {
        int p = atomicAdd(&fill[m * NN + d], 1);
        sm[(long long)m * MNZ + p] = make_int2(msrc[idx], __float_as_int(mval[idx]));
    }
}

__global__ __launch_bounds__(256) void k_scat_e(const int* __restrict__ ei,
                                                const float* __restrict__ ew,
                                                int* __restrict__ fill,
                                                int2* __restrict__ se) {
    int slice = blockIdx.x & 7;
    int e = (blockIdx.x >> 3) * 256 + threadIdx.x;
    int d = ei[NE + e];
    if (d / SLICE_W == slice) {
        int p = atomicAdd(&fill[d], 1);
        se[p] = make_int2(ei[e], __float_as_int(ew[e]));
    }
}

// ---------------- K2': edge gather  H[d] = sum w * XW[src]  -------------------
// One 16-lane quad per dst node; lane handles 4 channels (float4).
__global__ __launch_bounds__(256) void k_gath_e(const int2* __restrict__ se,
                                                const int* __restrict__ off,
                                                const int* __restrict__ cnt,
                                                const float* __restrict__ XW,
                                                float* __restrict__ H) {
    int sub = threadIdx.x >> 4, l = threadIdx.x & 15;
    int d = blockIdx.x * 16 + sub;
    int o = off[d], c = cnt[d];
    const int2* ep = se + o;
    floatx4 acc = (floatx4)0.f;
    int e = 0;
    for (; e + 1 < c; e += 2) {
        int2 a = ep[e], b = ep[e + 1];
        floatx4 ha = *(const floatx4*)&XW[(long long)a.x * 64 + l * 4];
        floatx4 hb = *(const floatx4*)&XW[(long long)b.x * 64 + l * 4];
        float va = __int_as_float(a.y), vb = __int_as_float(b.y);
#pragma unroll
        for (int q = 0; q < 4; ++q) acc[q] = fmaf(va, ha[q], acc[q]);
#pragma unroll
        for (int q = 0; q < 4; ++q) acc[q] = fmaf(vb, hb[q], acc[q]);
    }
    if (e < c) {
        int2 a = ep[e];
        floatx4 ha = *(const floatx4*)&XW[(long long)a.x * 64 + l * 4];
        float va = __int_as_float(a.y);
#pragma unroll
        for (int q = 0; q < 4; ++q) acc[q] = fmaf(va, ha[q], acc[q]);
    }
    *(floatx4*)&H[(long long)d * 64 + l * 4] = acc;
}

// ---------------- K3: h = h*norm + x@root + bias; Rb chunk0 = bf16(h) ---------
__global__ __launch_bounds__(256) void k_fin(const float* __restrict__ x,
                                             const float* __restrict__ root,
                                             const float* __restrict__ bias,
                                             const int* __restrict__ cnt_e,
                                             float* __restrict__ H,
                                             unsigned short* __restrict__ Rb) {
    __shared__ float Wl[64 * 64];
    __shared__ float xl[4][64];
    int t = threadIdx.x;
    for (int s = t; s < 4096; s += 256) Wl[s] = root[s];
    int nl = t >> 6, d = t & 63;
    int n = blockIdx.x * 4 + nl;
    xl[nl][d] = x[n * 64 + d];
    __syncthreads();
    float acc = 0.f;
#pragma unroll
    for (int k = 0; k < 64; ++k) acc = fmaf(xl[nl][k], Wl[k * 64 + d], acc);
    int dg = cnt_e[n];
    float nm = dg > 0 ? 1.0f / (float)dg : 0.f;
    long long idx = (long long)n * 64 + d;
    float hv = H[idx] * nm + acc + bias[d];
    H[idx] = hv;
    Rb[idx] = f2bf(hv);   // chunk 0 of chunk-major Rb [14][NN][64]
}

// ---------------- K4': motif gather  Rb[m+1][d] = bf16(sum v * H[src]) --------
__global__ __launch_bounds__(256) void k_gath_m(const int2* __restrict__ sm,
                                                const int* __restrict__ off,
                                                const int* __restrict__ cnt,
                                                const float* __restrict__ H,
                                                unsigned short* __restrict__ Rb) {
    int m = blockIdx.y;
    int sub = threadIdx.x >> 4, l = threadIdx.x & 15;
    int d = blockIdx.x * 16 + sub;
    long long mi = (long long)m * NN + d;
    int o = off[mi], c = cnt[mi];
    const int2* ep = sm + (long long)m * MNZ + o;
    floatx4 acc = (floatx4)0.f;
    int e = 0;
    for (; e + 1 < c; e += 2) {
        int2 a = ep[e], b = ep[e + 1];
        floatx4 ha = *(const floatx4*)&H[(long long)a.x * 64 + l * 4];
        floatx4 hb = *(const floatx4*)&H[(long long)b.x * 64 + l * 4];
        float va = __int_as_float(a.y), vb = __int_as_float(b.y);
#pragma unroll
        for (int q = 0; q < 4; ++q) acc[q] = fmaf(va, ha[q], acc[q]);
#pragma unroll
        for (int q = 0; q < 4; ++q) acc[q] = fmaf(vb, hb[q], acc[q]);
    }
    if (e < c) {
        int2 a = ep[e];
        floatx4 ha = *(const floatx4*)&H[(long long)a.x * 64 + l * 4];
        float va = __int_as_float(a.y);
#pragma unroll
        for (int q = 0; q < 4; ++q) acc[q] = fmaf(va, ha[q], acc[q]);
    }
    unsigned int lo = (unsigned int)f2bf(acc[0]) | ((unsigned int)f2bf(acc[1]) << 16);
    unsigned int hi = (unsigned int)f2bf(acc[2]) | ((unsigned int)f2bf(acc[3]) << 16);
    *(uint2*)&Rb[((long long)(m + 1) * NN + d) * 64 + l * 4] = make_uint2(lo, hi);
}

// ---------------- K5: build WT (Wbig^T) in bf16: [832 cols][896 k] ------------
__global__ void k_wt(const float* __restrict__ mW, unsigned short* __restrict__ WT) {
    int n = blockIdx.y;                        // 0..831
    int k = blockIdx.x * 128 + threadIdx.x;    // 0..895
    int i = (n >> 6) + 1;
    int d = n & 63;
    int r = k >> 6;
    int kk = k & 63;
    float v = 0.f;
    if (r != i) {
        int j = (r < i) ? r : r - 1;
        v = mW[((long long)(i - 1) * 832 + (j * 64 + kk)) * 64 + d];
    }
    WT[(long long)n * 896 + k] = f2bf(v);
}

// ---------------- K6: fused GEMM + mw + attention -----------------------------
// grid (13, 782): x = motif col-block, y = 128-row tile. 256 thr = 4 waves.
// A read directly as bf16 from chunk-major Rb [14][NN][64].
#define BM 128
#define LDA 72   // bf16 elems per LDS row (72*2=144B, 16B aligned, 2-way banks)

__global__ __launch_bounds__(256) void k_gemm(const unsigned short* __restrict__ Rb,
                                              const unsigned short* __restrict__ WT,
                                              const float* __restrict__ wa,
                                              const float* __restrict__ ba,
                                              const float* __restrict__ mb,
                                              float* __restrict__ out) {
    int im1 = blockIdx.x;          // 0..12, motif i = im1+1
    int i = im1 + 1;
    int row0 = blockIdx.y * BM;
    int t = threadIdx.x;
    int w = t >> 6;
    int lane = t & 63;
    int quad = lane >> 4;
    int l16 = lane & 15;

    __shared__ __align__(16) unsigned short Al[BM * LDA];
    __shared__ __align__(16) unsigned short Bl[64 * LDA];
    __shared__ __align__(16) unsigned short waTl[64 * LDA];

    // stage wa^T once: waTl[d][k] = bf16(wa[k][d])
    for (int s = t; s < 4096; s += 256) {
        int k = s >> 6, d = s & 63;
        waTl[d * LDA + k] = f2bf(wa[s]);
    }

    floatx4 acc[2][4];   // c accumulator: [m-tile][n-tile]
    floatx4 mwa[2][4];   // mw accumulator
#pragma unroll
    for (int a = 0; a < 2; ++a)
#pragma unroll
        for (int b = 0; b < 4; ++b) { acc[a][b] = (floatx4)0.f; mwa[a][b] = (floatx4)0.f; }

    // kb 0..13: main K loop (c).  kb==14: mw pass (A chunk r=i, B = wa^T).
    for (int kb = 0; kb < 15; ++kb) {
        int kchunk = (kb < 14) ? kb : i;
        __syncthreads();
        // stage A: 128 rows x 64 k, already bf16 (short8 global loads)
#pragma unroll
        for (int s = 0; s < 4; ++s) {
            int lin = t + s * 256;           // short8 index 0..1023
            int rr = lin >> 3;               // row 0..127
            int k8 = (lin & 7) * 8;          // k 0..56
            int grow = row0 + rr;
            short8 v = (short8)0;
            if (grow < NN) v = *(const short8*)&Rb[((long long)kchunk * NN + grow) * 64 + k8];
            *(short8*)&Al[rr * LDA + k8] = v;
        }
        if (kb < 14) {
            // stage B chunk from WT (already bf16): 64 rows x 64 k
#pragma unroll
            for (int s = 0; s < 4; ++s) {
                int lin4 = t + s * 256;      // ushort4 index 0..1023
                int n = lin4 >> 4;
                int k4 = (lin4 & 15) * 4;
                const unsigned short* src = &WT[(long long)(im1 * 64 + n) * 896 + kb * 64 + k4];
                *(unsigned long long*)&Bl[n * LDA + k4] = *(const unsigned long long*)src;
            }
        }
        __syncthreads();
#pragma unroll
        for (int kk = 0; kk < 64; kk += 32) {
            short8 af[2];
#pragma unroll
            for (int mt = 0; mt < 2; ++mt)
                af[mt] = *(const short8*)&Al[((w * 2 + mt) * 16 + l16) * LDA + kk + quad * 8];
            if (kb < 14) {
#pragma unroll
                for (int nt = 0; nt < 4; ++nt) {
                    short8 bf = *(const short8*)&Bl[(nt * 16 + l16) * LDA + kk + quad * 8];
#pragma unroll
                    for (int mt = 0; mt < 2; ++mt)
                        acc[mt][nt] = __builtin_amdgcn_mfma_f32_16x16x32_bf16(af[mt], bf, acc[mt][nt], 0, 0, 0);
                }
            } else {
#pragma unroll
                for (int nt = 0; nt < 4; ++nt) {
                    short8 bf = *(const short8*)&waTl[(nt * 16 + l16) * LDA + kk + quad * 8];
#pragma unroll
                    for (int mt = 0; mt < 2; ++mt)
                        mwa[mt][nt] = __builtin_amdgcn_mfma_f32_16x16x32_bf16(af[mt], bf, mwa[mt][nt], 0, 0, 0);
                }
            }
        }
    }

    // epilogue: c += mb, mw += ba; att = sigmoid(sum_d mw*c); out = att*(mw-c)
#pragma unroll
    for (int mt = 0; mt < 2; ++mt) {
        float cv[4][4], mv[4][4];   // [nt][reg]
#pragma unroll
        for (int nt = 0; nt < 4; ++nt) {
            int col = nt * 16 + l16;
            float mbv = mb[im1 * 64 + col];
            float bav = ba[col];
#pragma unroll
            for (int r = 0; r < 4; ++r) {
                cv[nt][r] = acc[mt][nt][r] + mbv;
                mv[nt][r] = mwa[mt][nt][r] + bav;
            }
        }
        int grow_base = row0 + (w * 2 + mt) * 16 + quad * 4;
#pragma unroll
        for (int r = 0; r < 4; ++r) {
            float s = 0.f;
#pragma unroll
            for (int nt = 0; nt < 4; ++nt) s += mv[nt][r] * cv[nt][r];
            s += __shfl_xor(s, 1);
            s += __shfl_xor(s, 2);
            s += __shfl_xor(s, 4);
            s += __shfl_xor(s, 8);   // full 64-col row sum within the 16-lane quad group
            float att = 1.f / (1.f + __expf(-s));
            int grow = grow_base + r;
            if (grow < NN) {
#pragma unroll
                for (int nt = 0; nt < 4; ++nt)
                    out[(long long)grow * 832 + im1 * 64 + nt * 16 + l16] = att * (mv[nt][r] - cv[nt][r]);
            }
        }
    }
}

// ------------------------------------------------------------------------------
extern "C" void kernel_launch(void* const* d_in, const int* in_sizes, int n_in,
                              void* d_out, int out_size, void* d_ws, size_t ws_size,
                              hipStream_t stream) {
    const float* x    = (const float*)d_in[0];
    const int*   ei   = (const int*)d_in[1];
    const float* ew   = (const float*)d_in[2];
    const int*   msrc = (const int*)d_in[3];
    const int*   mdst = (const int*)d_in[4];
    const float* mval = (const float*)d_in[5];
    const float* Wrel = (const float*)d_in[6];
    const float* root = (const float*)d_in[7];
    const float* bias = (const float*)d_in[8];
    const float* wa   = (const float*)d_in[9];
    const float* ba   = (const float*)d_in[10];
    const float* mW   = (const float*)d_in[11];
    const float* mb   = (const float*)d_in[12];
    float* out = (float*)d_out;

    // workspace layout (~345 MB)
    unsigned short* Rb = (unsigned short*)d_ws;                 // [14][NN][64] bf16 (chunk-major)
    float* H  = (float*)(Rb + (size_t)14 * NN * 64);            // [NN][64] fp32
    float* XW = H + (size_t)NN * 64;                            // [NN][64] fp32
    unsigned short* WT = (unsigned short*)(XW + (size_t)NN * 64); // [832][896] bf16
    int2* sm = (int2*)(WT + (size_t)832 * 896);                 // [13][MNZ] {src,val}
    int2* se = sm + (size_t)NM * MNZ;                           // [NE] {src,w}
    int* cnt_m  = (int*)(se + NE);                              // [13][NN]
    int* cnt_e  = cnt_m + (size_t)NM * NN;                      // [NN]
    int* cursors = cnt_e + NN;                                  // [16]
    int* off_m  = cursors + 16;                                 // [13][NN]
    int* fill_m = off_m + (size_t)NM * NN;                      // [13][NN]
    int* off_e  = fill_m + (size_t)NM * NN;                     // [NN]
    int* fill_e = off_e + NN;                                   // [NN]

    // zero cnt_m + cnt_e + cursors in one shot (contiguous)
    hipMemsetAsync(cnt_m, 0, sizeof(int) * ((size_t)NM * NN + NN + 16), stream);

    k_xw<<<NN / 4, 256, 0, stream>>>(x, Wrel, XW);
    k_hist_m<<<dim3(MNZ / 256, NM), 256, 0, stream>>>(mdst, cnt_m);
    k_hist_e<<<NE / 256, 256, 0, stream>>>(ei, cnt_e);
    k_alloc<<<dim3((NN + 255) / 256, NM), 256, 0, stream>>>(cnt_m, off_m, fill_m, cursors, NN);
    k_alloc<<<dim3((NN + 255) / 256, 1), 256, 0, stream>>>(cnt_e, off_e, fill_e, cursors + NM, NN);
    k_scat_m<<<dim3((MNZ / 256) * 8, NM), 256, 0, stream>>>(msrc, mdst, mval, fill_m, sm);
    k_scat_e<<<(NE / 256) * 8, 256, 0, stream>>>(ei, ew, fill_e, se);
    k_gath_e<<<NN / 16, 256, 0, stream>>>(se, off_e, cnt_e, XW, H);
    k_fin<<<NN / 4, 256, 0, stream>>>(x, root, bias, cnt_e, H, Rb);
    k_gath_m<<<dim3(NN / 16, NM), 256, 0, stream>>>(sm, off_m, cnt_m, H, Rb);
    k_wt<<<dim3(7, 832), 128, 0, stream>>>(mW, WT);
    k_gemm<<<dim3(NM, (NN + BM - 1) / BM), 256, 0, stream>>>(Rb, WT, wa, ba, mb, out);
}